// Round 1
// baseline (554.756 us; speedup 1.0000x reference)
//
#include <hip/hip_runtime.h>
#include <math.h>

#define T_DIM   1024
#define B_DIM   32
#define N_FEAT  1024
#define KW      3
#define NT      32                 // t-chunks for weighted-V pass
#define T_PER   (T_DIM / NT)       // 32
#define TT      32                 // t's per row_dots block
#define EPS     1e-6f

// Branchless tanh via exp2 pipe: ~8 VALU ops, |err| ~1e-7 (vs lib tanhf's
// branchy ~40-instr path). Clamp keeps exp finite; copysign restores sign.
__device__ __forceinline__ float tanh_fast(float x) {
  float ax = fminf(fabsf(x), 10.f);
  float e  = __expf(ax + ax);                            // exp(2|x|)
  float r  = fmaf(-2.f, __builtin_amdgcn_rcpf(e + 1.f), 1.f);
  return copysignf(r, x);
}

// ---------------------------------------------------------------------------
// Kernel 1: fused prep GEMV for BOTH weight matrices, m-outer ordering.
//   wid = m*32 + b  →  32 consecutive waves reuse one W row (weights read ~1x
//   from HBM instead of 32x). qk outputs are written TRANSPOSED to
//   kern_t[b][w][c] so row_dots can read 3 contiguous planes.
// ---------------------------------------------------------------------------
__global__ void __launch_bounds__(256) prep_kernel(
    const float* __restrict__ q1, const float* __restrict__ sa_w,
    const float* __restrict__ sa_b, const float* __restrict__ q2,
    const float* __restrict__ qk_w, const float* __restrict__ qk_b,
    float* __restrict__ sa_q, float* __restrict__ kern_t) {
  int wid  = (blockIdx.x * 256 + threadIdx.x) >> 6;   // 0 .. 4096*32-1
  int lane = threadIdx.x & 63;
  int b = wid & (B_DIM - 1);
  int m = wid >> 5;                                   // 0..4095 (uniform/wave)
  const float4* xr;
  const float4* wr;
  if (m < 1024) {
    xr = (const float4*)(q1 + (size_t)b * N_FEAT);
    wr = (const float4*)(sa_w + (size_t)m * N_FEAT);
  } else {
    xr = (const float4*)(q2 + (size_t)b * N_FEAT);
    wr = (const float4*)(qk_w + (size_t)(m - 1024) * N_FEAT);
  }
  float acc = 0.f;
#pragma unroll
  for (int i = 0; i < 4; i++) {
    float4 xv = xr[lane + 64 * i], wv = wr[lane + 64 * i];
    acc += xv.x * wv.x + xv.y * wv.y + xv.z * wv.z + xv.w * wv.w;
  }
#pragma unroll
  for (int off = 32; off > 0; off >>= 1) acc += __shfl_down(acc, off, 64);
  if (lane == 0) {
    if (m < 1024) {
      sa_q[(size_t)b * N_FEAT + m] = acc + sa_b[m];
    } else {
      int mm = m - 1024;
      int c = mm / 3, w = mm - 3 * c;                 // reshape(B,K2,KW) order
      kern_t[(size_t)b * (N_FEAT * KW) + (size_t)w * N_FEAT + c] = acc + qk_b[mm];
    }
  }
}

// ---------------------------------------------------------------------------
// Kernel 2: per-(t,b) row dots over k1 and k2 (the 256 MiB read pass).
// One block per (b, 32-t-slab): cached operands (sa_q row, a1_w, kern planes)
// staged in LDS ONCE per 32 rows instead of refetched per row; k1/k2 rows
// streamed with next-row register prefetch (16 b128 loads in flight / wave).
// Wave w handles t = t0 + 4i + w → wave-level shfl reduce, no __syncthreads
// in the main loop.
// ---------------------------------------------------------------------------
__global__ void __launch_bounds__(256, 4) row_dots_kernel(
    const float* __restrict__ k1, const float* __restrict__ k2,
    const float* __restrict__ sa_q, const float* __restrict__ a1_w,
    const float* __restrict__ kern_t, const float* __restrict__ a1_b,
    float* __restrict__ a1_out, float* __restrict__ s_out) {
  int b   = blockIdx.x;
  int t0  = blockIdx.y * TT;
  int tid = threadIdx.x, wave = tid >> 6, lane = tid & 63;

  __shared__ float kw_s[KW][N_FEAT];    // 12 KB, [w][c] planes
  __shared__ float sq_s[N_FEAT];        // 4 KB
  __shared__ float aw_s[N_FEAT];        // 4 KB
  {
    const float4* src = (const float4*)(kern_t + (size_t)b * (N_FEAT * KW));
    float4* dst = (float4*)&kw_s[0][0];
#pragma unroll
    for (int i = 0; i < 3; i++) dst[tid + 256 * i] = src[tid + 256 * i];
    ((float4*)sq_s)[tid] = ((const float4*)(sa_q + (size_t)b * N_FEAT))[tid];
    ((float4*)aw_s)[tid] = ((const float4*)a1_w)[tid];
  }
  __syncthreads();
  float a1bv = a1_b[0];

  float4 c1[4], c2[4];
  {
    size_t rb = ((size_t)(t0 + wave) * B_DIM + b) * N_FEAT;
#pragma unroll
    for (int ch = 0; ch < 4; ch++) {
      c1[ch] = *(const float4*)(k1 + rb + ch * 256 + lane * 4);
      c2[ch] = *(const float4*)(k2 + rb + ch * 256 + lane * 4);
    }
  }
  for (int i = 0; i < TT / 4; i++) {
    int t = t0 + 4 * i + wave;
    float4 n1[4], n2[4];
    if (i + 1 < TT / 4) {                       // prefetch next row pair
      size_t nb = ((size_t)(t + 4) * B_DIM + b) * N_FEAT;
#pragma unroll
      for (int ch = 0; ch < 4; ch++) {
        n1[ch] = *(const float4*)(k1 + nb + ch * 256 + lane * 4);
        n2[ch] = *(const float4*)(k2 + nb + ch * 256 + lane * 4);
      }
    } else {
#pragma unroll
      for (int ch = 0; ch < 4; ch++) { n1[ch] = c1[ch]; n2[ch] = c2[ch]; }
    }
    float p1 = 0.f, s0 = 0.f, s1 = 0.f, s2 = 0.f;
#pragma unroll
    for (int ch = 0; ch < 4; ch++) {
      int f = ch * 256 + lane * 4;
      float4 A  = c1[ch], Bv = c2[ch];
      float4 sq = *(const float4*)&sq_s[f];
      float4 aw = *(const float4*)&aw_s[f];
      p1 += tanh_fast(A.x + sq.x) * aw.x;
      p1 += tanh_fast(A.y + sq.y) * aw.y;
      p1 += tanh_fast(A.z + sq.z) * aw.z;
      p1 += tanh_fast(A.w + sq.w) * aw.w;
      float4 w0 = *(const float4*)&kw_s[0][f];
      float4 w1 = *(const float4*)&kw_s[1][f];
      float4 w2 = *(const float4*)&kw_s[2][f];
      s0 += Bv.x * w0.x + Bv.y * w0.y + Bv.z * w0.z + Bv.w * w0.w;
      s1 += Bv.x * w1.x + Bv.y * w1.y + Bv.z * w1.z + Bv.w * w1.w;
      s2 += Bv.x * w2.x + Bv.y * w2.y + Bv.z * w2.z + Bv.w * w2.w;
    }
#pragma unroll
    for (int off = 32; off > 0; off >>= 1) {
      p1 += __shfl_xor(p1, off, 64);
      s0 += __shfl_xor(s0, off, 64);
      s1 += __shfl_xor(s1, off, 64);
      s2 += __shfl_xor(s2, off, 64);
    }
    if (lane == 0) {
      size_t o = (size_t)t * B_DIM + b;
      a1_out[o] = p1 + a1bv;
      s_out[o * 3 + 0] = s0;
      s_out[o * 3 + 1] = s1;
      s_out[o * 3 + 2] = s2;
    }
#pragma unroll
    for (int ch = 0; ch < 4; ch++) { c1[ch] = n1[ch]; c2[ch] = n2[ch]; }
  }
}

// ---------------------------------------------------------------------------
// Block reduce helper (256 threads = 4 waves), broadcast result to all.
// ---------------------------------------------------------------------------
__device__ __forceinline__ float block_reduce_256(float v, bool is_max,
                                                  float* sm /*[4]*/) {
#pragma unroll
  for (int off = 32; off > 0; off >>= 1) {
    float o = __shfl_down(v, off, 64);
    v = is_max ? fmaxf(v, o) : v + o;
  }
  int wave = threadIdx.x >> 6;
  if ((threadIdx.x & 63) == 0) sm[wave] = v;
  __syncthreads();
  float r = is_max ? fmaxf(fmaxf(sm[0], sm[1]), fmaxf(sm[2], sm[3]))
                   : sm[0] + sm[1] + sm[2] + sm[3];
  __syncthreads();
  return r;
}

// ---------------------------------------------------------------------------
// Kernel 3: masked softmax over T for both paths. One block per b.
//   a2[t,b] = s[t-1,b,0] + s[t,b,1] + s[t+1,b,2]  (zero pad at edges)
// ---------------------------------------------------------------------------
__global__ void __launch_bounds__(256) softmax_kernel(
    const float* __restrict__ a1, const float* __restrict__ s,
    const float* __restrict__ k_mask,
    float* __restrict__ e1, float* __restrict__ e2) {
  int b = blockIdx.x;
  int tid = threadIdx.x;
  __shared__ float sm[4];

  float x1[4], x2[4], mk[4];
#pragma unroll
  for (int k = 0; k < 4; k++) {
    int t = tid + k * 256;
    x1[k] = a1[(size_t)t * B_DIM + b];
    float sl = (t > 0)         ? s[((size_t)(t - 1) * B_DIM + b) * 3 + 0] : 0.f;
    float sc =                   s[((size_t)t       * B_DIM + b) * 3 + 1];
    float sr = (t < T_DIM - 1) ? s[((size_t)(t + 1) * B_DIM + b) * 3 + 2] : 0.f;
    x2[k] = sl + sc + sr;
    mk[k] = k_mask[(size_t)t * B_DIM + b];
  }
  float m1 = fmaxf(fmaxf(x1[0], x1[1]), fmaxf(x1[2], x1[3]));
  float m2 = fmaxf(fmaxf(x2[0], x2[1]), fmaxf(x2[2], x2[3]));
  m1 = block_reduce_256(m1, true, sm);
  m2 = block_reduce_256(m2, true, sm);

  float v1[4], v2[4], sum1 = 0.f, sum2 = 0.f;
#pragma unroll
  for (int k = 0; k < 4; k++) {
    v1[k] = __expf(x1[k] - m1) * mk[k];
    v2[k] = __expf(x2[k] - m2) * mk[k];
    sum1 += v1[k];
    sum2 += v2[k];
  }
  sum1 = block_reduce_256(sum1, false, sm);
  sum2 = block_reduce_256(sum2, false, sm);
  float i1 = 1.f / sum1, i2 = 1.f / sum2;
#pragma unroll
  for (int k = 0; k < 4; k++) {
    int t = tid + k * 256;
    e1[(size_t)t * B_DIM + b] = v1[k] * i1;
    e2[(size_t)t * B_DIM + b] = v2[k] * i2;
  }
}

// ---------------------------------------------------------------------------
// Kernel 5: weighted sum over V for both paths (the other 256 MiB pass).
// grid = (B, NT=32) → 1024 blocks (4/CU, 16 waves/CU); unroll 8 keeps ~16
// b128 loads in flight per wave to cover HBM latency.
// ---------------------------------------------------------------------------
__global__ void __launch_bounds__(256) weighted_v_kernel(
    const float* __restrict__ v1, const float* __restrict__ v2,
    const float* __restrict__ e1, const float* __restrict__ e2,
    float* __restrict__ partial) {
  int b  = blockIdx.x;
  int tc = blockIdx.y;
  int tid = threadIdx.x;
  __shared__ float se1[T_PER], se2[T_PER];
  if (tid < T_PER)
    se1[tid] = e1[(size_t)(tc * T_PER + tid) * B_DIM + b];
  else if (tid < 2 * T_PER)
    se2[tid - T_PER] = e2[(size_t)(tc * T_PER + (tid - T_PER)) * B_DIM + b];
  __syncthreads();

  float4 acc1 = {0.f, 0.f, 0.f, 0.f}, acc2 = {0.f, 0.f, 0.f, 0.f};
  size_t dofs = (size_t)tid * 4;
#pragma unroll 8
  for (int i = 0; i < T_PER; i++) {
    size_t row = ((size_t)(tc * T_PER + i) * B_DIM + b) * N_FEAT + dofs;
    float4 a = *(const float4*)(v1 + row);
    float4 c = *(const float4*)(v2 + row);
    float w1 = se1[i], w2 = se2[i];
    acc1.x = fmaf(w1, a.x, acc1.x); acc1.y = fmaf(w1, a.y, acc1.y);
    acc1.z = fmaf(w1, a.z, acc1.z); acc1.w = fmaf(w1, a.w, acc1.w);
    acc2.x = fmaf(w2, c.x, acc2.x); acc2.y = fmaf(w2, c.y, acc2.y);
    acc2.z = fmaf(w2, c.z, acc2.z); acc2.w = fmaf(w2, c.w, acc2.w);
  }
  size_t o1 = ((size_t)(0 * NT + tc) * B_DIM + b) * N_FEAT + dofs;
  size_t o2 = ((size_t)(1 * NT + tc) * B_DIM + b) * N_FEAT + dofs;
  *(float4*)(partial + o1) = acc1;
  *(float4*)(partial + o2) = acc2;
}

// ---------------------------------------------------------------------------
// Kernel 6: reduce partials, add paths, LayerNorm over feature dim.
// One block per b, 1024 threads (16 waves).
// ---------------------------------------------------------------------------
__device__ __forceinline__ float block_reduce_sum_1024(float v, float* sm) {
#pragma unroll
  for (int off = 32; off > 0; off >>= 1) v += __shfl_down(v, off, 64);
  int wave = threadIdx.x >> 6;
  if ((threadIdx.x & 63) == 0) sm[wave] = v;
  __syncthreads();
  float tot = 0.f;
#pragma unroll
  for (int i = 0; i < 16; i++) tot += sm[i];
  __syncthreads();
  return tot;
}

__global__ void __launch_bounds__(1024) ln_kernel(
    const float* __restrict__ partial, const float* __restrict__ ln_g,
    const float* __restrict__ ln_b, float* __restrict__ out) {
  int b = blockIdx.x;
  int d = threadIdx.x;
  __shared__ float sm[16];
  float x = 0.f;
#pragma unroll
  for (int j = 0; j < 2 * NT; j++)
    x += partial[((size_t)j * B_DIM + b) * N_FEAT + d];
  float ssum = block_reduce_sum_1024(x, sm);
  float mu = ssum * (1.f / N_FEAT);
  float dx = x - mu;
  float vsum = block_reduce_sum_1024(dx * dx, sm);
  float inv = rsqrtf(vsum * (1.f / N_FEAT) + EPS);
  out[(size_t)b * N_FEAT + d] = dx * inv * ln_g[d] + ln_b[d];
}

// ---------------------------------------------------------------------------
extern "C" void kernel_launch(void* const* d_in, const int* in_sizes, int n_in,
                              void* d_out, int out_size, void* d_ws, size_t ws_size,
                              hipStream_t stream) {
  const float* q1     = (const float*)d_in[0];
  const float* k1     = (const float*)d_in[1];
  const float* v1     = (const float*)d_in[2];
  const float* q2     = (const float*)d_in[3];
  const float* k2     = (const float*)d_in[4];
  const float* v2     = (const float*)d_in[5];
  const float* k_mask = (const float*)d_in[6];
  const float* sa_w   = (const float*)d_in[7];
  const float* sa_b   = (const float*)d_in[8];
  const float* a1_w   = (const float*)d_in[9];
  const float* a1_b   = (const float*)d_in[10];
  const float* qk_w   = (const float*)d_in[11];
  const float* qk_b   = (const float*)d_in[12];
  const float* ln_g   = (const float*)d_in[13];
  const float* ln_bp  = (const float*)d_in[14];
  float* out = (float*)d_out;
  float* ws  = (float*)d_ws;
  (void)k_mask;

  // ws layout (floats)
  float* sa_q    = ws;                       // 32768
  float* kern_t  = sa_q + 32768;             // 98304  [b][w][c] (transposed!)
  float* s       = kern_t + 98304;           // 98304  [t][b][w]
  float* a1      = s + 98304;                // 32768  [t][b]
  float* e1      = a1 + 32768;               // 32768
  float* e2      = e1 + 32768;               // 32768
  float* partial = e2 + 32768;               // 2*NT*B*N = 2097152 (8 MiB)

  // 1) both GEMVs fused, m-outer for weight reuse; kern written transposed
  prep_kernel<<<dim3((4096 * B_DIM) / 4), 256, 0, stream>>>(
      q1, sa_w, sa_b, q2, qk_w, qk_b, sa_q, kern_t);
  // 2) a1 + conv taps s                  (reads k1, k2: 256 MiB)
  row_dots_kernel<<<dim3(B_DIM, T_DIM / TT), 256, 0, stream>>>(
      k1, k2, sa_q, a1_w, kern_t, a1_b, a1, s);
  // 3) softmax both paths
  softmax_kernel<<<dim3(B_DIM), 256, 0, stream>>>(a1, s, k_mask, e1, e2);
  // 4) weighted V sums                   (reads v1, v2: 256 MiB)
  weighted_v_kernel<<<dim3(B_DIM, NT), 256, 0, stream>>>(v1, v2, e1, e2, partial);
  // 5) combine + LayerNorm
  ln_kernel<<<dim3(B_DIM), 1024, 0, stream>>>(partial, ln_g, ln_bp, out);
}

// Round 2
// 538.130 us; speedup vs baseline: 1.0309x; 1.0309x over previous
//
#include <hip/hip_runtime.h>
#include <math.h>

#define T_DIM   1024
#define B_DIM   32
#define N_FEAT  1024
#define KW      3
#define NT      32                 // t-chunks for weighted-V pass
#define T_PER   (T_DIM / NT)       // 32
#define EPS     1e-6f

// Branchless tanh via exp pipe: ~8 VALU ops, |err| ~1e-7 (vs lib tanhf's
// branchy ~40+ instr path). Proven round 1: VALUBusy 43% -> 12%.
__device__ __forceinline__ float tanh_fast(float x) {
  float ax = fminf(fabsf(x), 10.f);
  float e  = __expf(ax + ax);                            // exp(2|x|)
  float r  = fmaf(-2.f, __builtin_amdgcn_rcpf(e + 1.f), 1.f);
  return copysignf(r, x);
}

// ---------------------------------------------------------------------------
// Kernel 1: fused prep GEMV for BOTH weight matrices, m-outer ordering.
//   wid = m*32 + b  →  32 consecutive waves reuse one W row (weights stream
//   1x from HBM instead of 32x as in the original b-outer gemv). qk outputs
//   are written TRANSPOSED to kern_t[b][w][c] so row_dots reads 3 contiguous
//   coalesced planes.
// ---------------------------------------------------------------------------
__global__ void __launch_bounds__(256) prep_kernel(
    const float* __restrict__ q1, const float* __restrict__ sa_w,
    const float* __restrict__ sa_b, const float* __restrict__ q2,
    const float* __restrict__ qk_w, const float* __restrict__ qk_b,
    float* __restrict__ sa_q, float* __restrict__ kern_t) {
  int wid  = (blockIdx.x * 256 + threadIdx.x) >> 6;   // 0 .. 4096*32-1
  int lane = threadIdx.x & 63;
  int b = wid & (B_DIM - 1);
  int m = wid >> 5;                                   // 0..4095 (uniform/wave)
  const float4* xr;
  const float4* wr;
  if (m < 1024) {
    xr = (const float4*)(q1 + (size_t)b * N_FEAT);
    wr = (const float4*)(sa_w + (size_t)m * N_FEAT);
  } else {
    xr = (const float4*)(q2 + (size_t)b * N_FEAT);
    wr = (const float4*)(qk_w + (size_t)(m - 1024) * N_FEAT);
  }
  float acc = 0.f;
#pragma unroll
  for (int i = 0; i < 4; i++) {
    float4 xv = xr[lane + 64 * i], wv = wr[lane + 64 * i];
    acc += xv.x * wv.x + xv.y * wv.y + xv.z * wv.z + xv.w * wv.w;
  }
#pragma unroll
  for (int off = 32; off > 0; off >>= 1) acc += __shfl_down(acc, off, 64);
  if (lane == 0) {
    if (m < 1024) {
      sa_q[(size_t)b * N_FEAT + m] = acc + sa_b[m];
    } else {
      int mm = m - 1024;
      int c = mm / 3, w = mm - 3 * c;                 // reshape(B,K2,KW) order
      kern_t[(size_t)b * (N_FEAT * KW) + (size_t)w * N_FEAT + c] = acc + qk_b[mm];
    }
  }
}

// ---------------------------------------------------------------------------
// Kernel 2: per-(t,b) row dots over k1 and k2 (the 256 MiB read pass).
// ROUND-0 GRID RESTORED: one 256-thread block per blk = t*B+b, so consecutive
// blocks read consecutive 4 KB rows — perfectly sequential HBM stream, L3
// absorbs ~half (FETCH 131 MB vs 247 MB for the slab order tried in R1).
// Cached operands (sa_q row, a1_w, kern_t planes — 516 KB total, L2-resident)
// are re-fetched per block: never visible in FETCH_SIZE, so no LDS staging.
// ---------------------------------------------------------------------------
__global__ void __launch_bounds__(256) row_dots_kernel(
    const float* __restrict__ k1, const float* __restrict__ k2,
    const float* __restrict__ sa_q, const float* __restrict__ a1_w,
    const float* __restrict__ kern_t, const float* __restrict__ a1_b,
    float* __restrict__ a1_out, float* __restrict__ s_out) {
  int blk = blockIdx.x;            // t*B + b
  int b   = blk & (B_DIM - 1);
  int tid = threadIdx.x;
  size_t row = (size_t)blk * N_FEAT + tid * 4;
  int f = tid * 4;

  float4 k1v = *(const float4*)(k1 + row);
  float4 sqv = *(const float4*)(sa_q + (size_t)b * N_FEAT + f);
  float4 awv = *(const float4*)(a1_w + f);
  float p1 = tanh_fast(k1v.x + sqv.x) * awv.x
           + tanh_fast(k1v.y + sqv.y) * awv.y
           + tanh_fast(k1v.z + sqv.z) * awv.z
           + tanh_fast(k1v.w + sqv.w) * awv.w;

  float4 k2v = *(const float4*)(k2 + row);
  const float* kb = kern_t + (size_t)b * (N_FEAT * KW);
  float4 w0 = *(const float4*)(kb + 0 * N_FEAT + f);
  float4 w1 = *(const float4*)(kb + 1 * N_FEAT + f);
  float4 w2 = *(const float4*)(kb + 2 * N_FEAT + f);
  float s0 = k2v.x * w0.x + k2v.y * w0.y + k2v.z * w0.z + k2v.w * w0.w;
  float s1 = k2v.x * w1.x + k2v.y * w1.y + k2v.z * w1.z + k2v.w * w1.w;
  float s2 = k2v.x * w2.x + k2v.y * w2.y + k2v.z * w2.z + k2v.w * w2.w;

  // block reduce 4 values across 4 waves
  float vals[4] = {p1, s0, s1, s2};
#pragma unroll
  for (int off = 32; off > 0; off >>= 1) {
#pragma unroll
    for (int j = 0; j < 4; j++) vals[j] += __shfl_down(vals[j], off, 64);
  }
  __shared__ float red[4][4];
  int wave = tid >> 6, lane = tid & 63;
  if (lane == 0) {
#pragma unroll
    for (int j = 0; j < 4; j++) red[wave][j] = vals[j];
  }
  __syncthreads();
  if (tid == 0) {
    float r0 = red[0][0] + red[1][0] + red[2][0] + red[3][0];
    float r1 = red[0][1] + red[1][1] + red[2][1] + red[3][1];
    float r2 = red[0][2] + red[1][2] + red[2][2] + red[3][2];
    float r3 = red[0][3] + red[1][3] + red[2][3] + red[3][3];
    a1_out[blk] = r0 + a1_b[0];
    s_out[(size_t)blk * 3 + 0] = r1;
    s_out[(size_t)blk * 3 + 1] = r2;
    s_out[(size_t)blk * 3 + 2] = r3;
  }
}

// ---------------------------------------------------------------------------
// Block reduce helper (256 threads = 4 waves), broadcast result to all.
// ---------------------------------------------------------------------------
__device__ __forceinline__ float block_reduce_256(float v, bool is_max,
                                                  float* sm /*[4]*/) {
#pragma unroll
  for (int off = 32; off > 0; off >>= 1) {
    float o = __shfl_down(v, off, 64);
    v = is_max ? fmaxf(v, o) : v + o;
  }
  int wave = threadIdx.x >> 6;
  if ((threadIdx.x & 63) == 0) sm[wave] = v;
  __syncthreads();
  float r = is_max ? fmaxf(fmaxf(sm[0], sm[1]), fmaxf(sm[2], sm[3]))
                   : sm[0] + sm[1] + sm[2] + sm[3];
  __syncthreads();
  return r;
}

// ---------------------------------------------------------------------------
// Kernel 3: masked softmax over T for both paths. One block per b.
//   a2[t,b] = s[t-1,b,0] + s[t,b,1] + s[t+1,b,2]  (zero pad at edges)
// ---------------------------------------------------------------------------
__global__ void __launch_bounds__(256) softmax_kernel(
    const float* __restrict__ a1, const float* __restrict__ s,
    const float* __restrict__ k_mask,
    float* __restrict__ e1, float* __restrict__ e2) {
  int b = blockIdx.x;
  int tid = threadIdx.x;
  __shared__ float sm[4];

  float x1[4], x2[4], mk[4];
#pragma unroll
  for (int k = 0; k < 4; k++) {
    int t = tid + k * 256;
    x1[k] = a1[(size_t)t * B_DIM + b];
    float sl = (t > 0)         ? s[((size_t)(t - 1) * B_DIM + b) * 3 + 0] : 0.f;
    float sc =                   s[((size_t)t       * B_DIM + b) * 3 + 1];
    float sr = (t < T_DIM - 1) ? s[((size_t)(t + 1) * B_DIM + b) * 3 + 2] : 0.f;
    x2[k] = sl + sc + sr;
    mk[k] = k_mask[(size_t)t * B_DIM + b];
  }
  float m1 = fmaxf(fmaxf(x1[0], x1[1]), fmaxf(x1[2], x1[3]));
  float m2 = fmaxf(fmaxf(x2[0], x2[1]), fmaxf(x2[2], x2[3]));
  m1 = block_reduce_256(m1, true, sm);
  m2 = block_reduce_256(m2, true, sm);

  float v1[4], v2[4], sum1 = 0.f, sum2 = 0.f;
#pragma unroll
  for (int k = 0; k < 4; k++) {
    v1[k] = __expf(x1[k] - m1) * mk[k];
    v2[k] = __expf(x2[k] - m2) * mk[k];
    sum1 += v1[k];
    sum2 += v2[k];
  }
  sum1 = block_reduce_256(sum1, false, sm);
  sum2 = block_reduce_256(sum2, false, sm);
  float i1 = 1.f / sum1, i2 = 1.f / sum2;
#pragma unroll
  for (int k = 0; k < 4; k++) {
    int t = tid + k * 256;
    e1[(size_t)t * B_DIM + b] = v1[k] * i1;
    e2[(size_t)t * B_DIM + b] = v2[k] * i2;
  }
}

// ---------------------------------------------------------------------------
// Kernel 4: weighted sum over V for both paths (the other 256 MiB pass).
// grid = (B, NT=32) → 1024 blocks (4/CU, 16 waves/CU); unroll 8 keeps ~16
// b128 loads in flight per wave to cover HBM latency. (R1 config — was fine.)
// ---------------------------------------------------------------------------
__global__ void __launch_bounds__(256) weighted_v_kernel(
    const float* __restrict__ v1, const float* __restrict__ v2,
    const float* __restrict__ e1, const float* __restrict__ e2,
    float* __restrict__ partial) {
  int b  = blockIdx.x;
  int tc = blockIdx.y;
  int tid = threadIdx.x;
  __shared__ float se1[T_PER], se2[T_PER];
  if (tid < T_PER)
    se1[tid] = e1[(size_t)(tc * T_PER + tid) * B_DIM + b];
  else if (tid < 2 * T_PER)
    se2[tid - T_PER] = e2[(size_t)(tc * T_PER + (tid - T_PER)) * B_DIM + b];
  __syncthreads();

  float4 acc1 = {0.f, 0.f, 0.f, 0.f}, acc2 = {0.f, 0.f, 0.f, 0.f};
  size_t dofs = (size_t)tid * 4;
#pragma unroll 8
  for (int i = 0; i < T_PER; i++) {
    size_t row = ((size_t)(tc * T_PER + i) * B_DIM + b) * N_FEAT + dofs;
    float4 a = *(const float4*)(v1 + row);
    float4 c = *(const float4*)(v2 + row);
    float w1 = se1[i], w2 = se2[i];
    acc1.x = fmaf(w1, a.x, acc1.x); acc1.y = fmaf(w1, a.y, acc1.y);
    acc1.z = fmaf(w1, a.z, acc1.z); acc1.w = fmaf(w1, a.w, acc1.w);
    acc2.x = fmaf(w2, c.x, acc2.x); acc2.y = fmaf(w2, c.y, acc2.y);
    acc2.z = fmaf(w2, c.z, acc2.z); acc2.w = fmaf(w2, c.w, acc2.w);
  }
  size_t o1 = ((size_t)(0 * NT + tc) * B_DIM + b) * N_FEAT + dofs;
  size_t o2 = ((size_t)(1 * NT + tc) * B_DIM + b) * N_FEAT + dofs;
  *(float4*)(partial + o1) = acc1;
  *(float4*)(partial + o2) = acc2;
}

// ---------------------------------------------------------------------------
// Kernel 5: reduce partials, add paths, LayerNorm over feature dim.
// One block per b, 1024 threads (16 waves).
// ---------------------------------------------------------------------------
__device__ __forceinline__ float block_reduce_sum_1024(float v, float* sm) {
#pragma unroll
  for (int off = 32; off > 0; off >>= 1) v += __shfl_down(v, off, 64);
  int wave = threadIdx.x >> 6;
  if ((threadIdx.x & 63) == 0) sm[wave] = v;
  __syncthreads();
  float tot = 0.f;
#pragma unroll
  for (int i = 0; i < 16; i++) tot += sm[i];
  __syncthreads();
  return tot;
}

__global__ void __launch_bounds__(1024) ln_kernel(
    const float* __restrict__ partial, const float* __restrict__ ln_g,
    const float* __restrict__ ln_b, float* __restrict__ out) {
  int b = blockIdx.x;
  int d = threadIdx.x;
  __shared__ float sm[16];
  float x = 0.f;
#pragma unroll
  for (int j = 0; j < 2 * NT; j++)
    x += partial[((size_t)j * B_DIM + b) * N_FEAT + d];
  float ssum = block_reduce_sum_1024(x, sm);
  float mu = ssum * (1.f / N_FEAT);
  float dx = x - mu;
  float vsum = block_reduce_sum_1024(dx * dx, sm);
  float inv = rsqrtf(vsum * (1.f / N_FEAT) + EPS);
  out[(size_t)b * N_FEAT + d] = dx * inv * ln_g[d] + ln_b[d];
}

// ---------------------------------------------------------------------------
extern "C" void kernel_launch(void* const* d_in, const int* in_sizes, int n_in,
                              void* d_out, int out_size, void* d_ws, size_t ws_size,
                              hipStream_t stream) {
  const float* q1     = (const float*)d_in[0];
  const float* k1     = (const float*)d_in[1];
  const float* v1     = (const float*)d_in[2];
  const float* q2     = (const float*)d_in[3];
  const float* k2     = (const float*)d_in[4];
  const float* v2     = (const float*)d_in[5];
  const float* k_mask = (const float*)d_in[6];
  const float* sa_w   = (const float*)d_in[7];
  const float* sa_b   = (const float*)d_in[8];
  const float* a1_w   = (const float*)d_in[9];
  const float* a1_b   = (const float*)d_in[10];
  const float* qk_w   = (const float*)d_in[11];
  const float* qk_b   = (const float*)d_in[12];
  const float* ln_g   = (const float*)d_in[13];
  const float* ln_bp  = (const float*)d_in[14];
  float* out = (float*)d_out;
  float* ws  = (float*)d_ws;

  // ws layout (floats)
  float* sa_q    = ws;                       // 32768
  float* kern_t  = sa_q + 32768;             // 98304  [b][w][c] (transposed!)
  float* s       = kern_t + 98304;           // 98304  [t][b][w]
  float* a1      = s + 98304;                // 32768  [t][b]
  float* e1      = a1 + 32768;               // 32768
  float* e2      = e1 + 32768;               // 32768
  float* partial = e2 + 32768;               // 2*NT*B*N = 2097152 (8 MiB)

  // 1) both GEMVs fused, m-outer for weight reuse; kern written transposed
  prep_kernel<<<dim3((4096 * B_DIM) / 4), 256, 0, stream>>>(
      q1, sa_w, sa_b, q2, qk_w, qk_b, sa_q, kern_t);
  // 2) a1 + conv taps s                  (reads k1, k2: 256 MiB, sequential)
  row_dots_kernel<<<dim3(T_DIM * B_DIM), 256, 0, stream>>>(
      k1, k2, sa_q, a1_w, kern_t, a1_b, a1, s);
  // 3) softmax both paths
  softmax_kernel<<<dim3(B_DIM), 256, 0, stream>>>(a1, s, k_mask, e1, e2);
  // 4) weighted V sums                   (reads v1, v2: 256 MiB)
  weighted_v_kernel<<<dim3(B_DIM, NT), 256, 0, stream>>>(v1, v2, e1, e2, partial);
  // 5) combine + LayerNorm
  ln_kernel<<<dim3(B_DIM), 1024, 0, stream>>>(partial, ln_g, ln_bp, out);
}

// Round 3
// 537.406 us; speedup vs baseline: 1.0323x; 1.0013x over previous
//
#include <hip/hip_runtime.h>
#include <math.h>

#define T_DIM   1024
#define B_DIM   32
#define N_FEAT  1024
#define KW      3
#define NT      32                 // t-chunks for weighted-V pass (partial layout)
#define EPS     1e-6f

#define RD_BLOCKS 2048             // persistent row_dots blocks (8/CU)
#define RD_RPB    (T_DIM * B_DIM / RD_BLOCKS)   // 16 rows per block
#define WV_BLOCKS (B_DIM * NT)     // 1024
#define WV_RPB    (T_DIM / NT)     // 32 rows per block

// Branchless tanh via exp pipe: ~8 VALU ops, |err| ~1e-7 (vs lib tanhf's
// branchy ~40+ instr path). Proven R1/R2: VALUBusy 43% -> 27%.
__device__ __forceinline__ float tanh_fast(float x) {
  float ax = fminf(fabsf(x), 10.f);
  float e  = __expf(ax + ax);                            // exp(2|x|)
  float r  = fmaf(-2.f, __builtin_amdgcn_rcpf(e + 1.f), 1.f);
  return copysignf(r, x);
}

// ---------------------------------------------------------------------------
// Kernel 1: fused prep GEMV for BOTH weight matrices, m-outer ordering.
// (unchanged from R2 — not in the hot set)
// ---------------------------------------------------------------------------
__global__ void __launch_bounds__(256) prep_kernel(
    const float* __restrict__ q1, const float* __restrict__ sa_w,
    const float* __restrict__ sa_b, const float* __restrict__ q2,
    const float* __restrict__ qk_w, const float* __restrict__ qk_b,
    float* __restrict__ sa_q, float* __restrict__ kern_t) {
  int wid  = (blockIdx.x * 256 + threadIdx.x) >> 6;   // 0 .. 4096*32-1
  int lane = threadIdx.x & 63;
  int b = wid & (B_DIM - 1);
  int m = wid >> 5;                                   // uniform per wave
  const float4* xr;
  const float4* wr;
  if (m < 1024) {
    xr = (const float4*)(q1 + (size_t)b * N_FEAT);
    wr = (const float4*)(sa_w + (size_t)m * N_FEAT);
  } else {
    xr = (const float4*)(q2 + (size_t)b * N_FEAT);
    wr = (const float4*)(qk_w + (size_t)(m - 1024) * N_FEAT);
  }
  float acc = 0.f;
#pragma unroll
  for (int i = 0; i < 4; i++) {
    float4 xv = xr[lane + 64 * i], wv = wr[lane + 64 * i];
    acc += xv.x * wv.x + xv.y * wv.y + xv.z * wv.z + xv.w * wv.w;
  }
#pragma unroll
  for (int off = 32; off > 0; off >>= 1) acc += __shfl_down(acc, off, 64);
  if (lane == 0) {
    if (m < 1024) {
      sa_q[(size_t)b * N_FEAT + m] = acc + sa_b[m];
    } else {
      int mm = m - 1024;
      int c = mm / 3, w = mm - 3 * c;                 // reshape(B,K2,KW) order
      kern_t[(size_t)b * (N_FEAT * KW) + (size_t)w * N_FEAT + c] = acc + qk_b[mm];
    }
  }
}

// ---------------------------------------------------------------------------
// Kernel 2: row dots, PERSISTENT same-b grid-stride form.
// Block g handles rows g, g+2048, ..., (16 rows). 2048 % 32 == 0 so b is
// block-invariant: the 20 floats of per-(b,f) operands (sa_q, a1_w, 3 kern
// planes) are loaded ONCE into registers (was 640 MB of L2 re-reads = 2.5x
// the stream). Instantaneous footprint across 2048 concurrent blocks is a
// contiguous 8 MB window sliding sequentially -> keeps R2's L3 absorption
// (unlike R1's slab order). Depth-2 register prefetch on the k1/k2 stream.
// ---------------------------------------------------------------------------
__global__ void __launch_bounds__(256, 4) row_dots_kernel(
    const float* __restrict__ k1, const float* __restrict__ k2,
    const float* __restrict__ sa_q, const float* __restrict__ a1_w,
    const float* __restrict__ kern_t, const float* __restrict__ a1_b,
    float* __restrict__ a1_out, float* __restrict__ s_out) {
  int g   = blockIdx.x;                 // 0..2047
  int b   = g & (B_DIM - 1);            // block-invariant
  int tid = threadIdx.x;
  int f   = tid * 4;
  int wave = tid >> 6, lane = tid & 63;
  __shared__ float red[2][4][4];        // double-buffered -> 1 sync per row

  // loop-invariant per-thread operand slice (20 floats in registers)
  float4 sqv = *(const float4*)(sa_q + (size_t)b * N_FEAT + f);
  float4 awv = *(const float4*)(a1_w + f);
  const float* kb = kern_t + (size_t)b * (N_FEAT * KW);
  float4 w0 = *(const float4*)(kb + 0 * N_FEAT + f);
  float4 w1 = *(const float4*)(kb + 1 * N_FEAT + f);
  float4 w2 = *(const float4*)(kb + 2 * N_FEAT + f);
  float a1bv = a1_b[0];

  // preload row 0 of the stream
  float4 c1 = *(const float4*)(k1 + (size_t)g * N_FEAT + f);
  float4 c2 = *(const float4*)(k2 + (size_t)g * N_FEAT + f);

  for (int i = 0; i < RD_RPB; i++) {
    int r  = g + (i << 11);                         // current row (t*B+b)
    int rn = (i + 1 < RD_RPB) ? r + RD_BLOCKS : r;  // clamped prefetch
    float4 n1 = *(const float4*)(k1 + (size_t)rn * N_FEAT + f);
    float4 n2 = *(const float4*)(k2 + (size_t)rn * N_FEAT + f);

    float p1 = tanh_fast(c1.x + sqv.x) * awv.x
             + tanh_fast(c1.y + sqv.y) * awv.y
             + tanh_fast(c1.z + sqv.z) * awv.z
             + tanh_fast(c1.w + sqv.w) * awv.w;
    float s0 = c2.x * w0.x + c2.y * w0.y + c2.z * w0.z + c2.w * w0.w;
    float s1 = c2.x * w1.x + c2.y * w1.y + c2.z * w1.z + c2.w * w1.w;
    float s2 = c2.x * w2.x + c2.y * w2.y + c2.z * w2.z + c2.w * w2.w;

    float vals[4] = {p1, s0, s1, s2};
#pragma unroll
    for (int off = 32; off > 0; off >>= 1) {
#pragma unroll
      for (int j = 0; j < 4; j++) vals[j] += __shfl_down(vals[j], off, 64);
    }
    int ph = i & 1;
    if (lane == 0) {
#pragma unroll
      for (int j = 0; j < 4; j++) red[ph][wave][j] = vals[j];
    }
    __syncthreads();
    if (tid == 0) {
      float r0 = red[ph][0][0] + red[ph][1][0] + red[ph][2][0] + red[ph][3][0];
      float r1 = red[ph][0][1] + red[ph][1][1] + red[ph][2][1] + red[ph][3][1];
      float r2 = red[ph][0][2] + red[ph][1][2] + red[ph][2][2] + red[ph][3][2];
      float r3 = red[ph][0][3] + red[ph][1][3] + red[ph][2][3] + red[ph][3][3];
      a1_out[r] = r0 + a1bv;
      s_out[(size_t)r * 3 + 0] = r1;
      s_out[(size_t)r * 3 + 1] = r2;
      s_out[(size_t)r * 3 + 2] = r3;
    }
    c1 = n1; c2 = n2;
  }
}

// ---------------------------------------------------------------------------
// Block reduce helper (256 threads = 4 waves), broadcast result to all.
// ---------------------------------------------------------------------------
__device__ __forceinline__ float block_reduce_256(float v, bool is_max,
                                                  float* sm /*[4]*/) {
#pragma unroll
  for (int off = 32; off > 0; off >>= 1) {
    float o = __shfl_down(v, off, 64);
    v = is_max ? fmaxf(v, o) : v + o;
  }
  int wave = threadIdx.x >> 6;
  if ((threadIdx.x & 63) == 0) sm[wave] = v;
  __syncthreads();
  float r = is_max ? fmaxf(fmaxf(sm[0], sm[1]), fmaxf(sm[2], sm[3]))
                   : sm[0] + sm[1] + sm[2] + sm[3];
  __syncthreads();
  return r;
}

// ---------------------------------------------------------------------------
// Kernel 3: masked softmax over T for both paths. One block per b.
//   a2[t,b] = s[t-1,b,0] + s[t,b,1] + s[t+1,b,2]  (zero pad at edges)
// ---------------------------------------------------------------------------
__global__ void __launch_bounds__(256) softmax_kernel(
    const float* __restrict__ a1, const float* __restrict__ s,
    const float* __restrict__ k_mask,
    float* __restrict__ e1, float* __restrict__ e2) {
  int b = blockIdx.x;
  int tid = threadIdx.x;
  __shared__ float sm[4];

  float x1[4], x2[4], mk[4];
#pragma unroll
  for (int k = 0; k < 4; k++) {
    int t = tid + k * 256;
    x1[k] = a1[(size_t)t * B_DIM + b];
    float sl = (t > 0)         ? s[((size_t)(t - 1) * B_DIM + b) * 3 + 0] : 0.f;
    float sc =                   s[((size_t)t       * B_DIM + b) * 3 + 1];
    float sr = (t < T_DIM - 1) ? s[((size_t)(t + 1) * B_DIM + b) * 3 + 2] : 0.f;
    x2[k] = sl + sc + sr;
    mk[k] = k_mask[(size_t)t * B_DIM + b];
  }
  float m1 = fmaxf(fmaxf(x1[0], x1[1]), fmaxf(x1[2], x1[3]));
  float m2 = fmaxf(fmaxf(x2[0], x2[1]), fmaxf(x2[2], x2[3]));
  m1 = block_reduce_256(m1, true, sm);
  m2 = block_reduce_256(m2, true, sm);

  float v1[4], v2[4], sum1 = 0.f, sum2 = 0.f;
#pragma unroll
  for (int k = 0; k < 4; k++) {
    v1[k] = __expf(x1[k] - m1) * mk[k];
    v2[k] = __expf(x2[k] - m2) * mk[k];
    sum1 += v1[k];
    sum2 += v2[k];
  }
  sum1 = block_reduce_256(sum1, false, sm);
  sum2 = block_reduce_256(sum2, false, sm);
  float i1 = 1.f / sum1, i2 = 1.f / sum2;
#pragma unroll
  for (int k = 0; k < 4; k++) {
    int t = tid + k * 256;
    e1[(size_t)t * B_DIM + b] = v1[k] * i1;
    e2[(size_t)t * B_DIM + b] = v2[k] * i2;
  }
}

// ---------------------------------------------------------------------------
// Kernel 4: weighted V sums, PERSISTENT same-b grid-stride form (same idea as
// row_dots: block g -> b = g&31, chunk = g>>5; rows g + 1024*i, i<32 -> the
// 1024 concurrent blocks sweep a contiguous 4 MB window sequentially instead
// of the old per-block 128 KB-strided slab walk). Partial layout identical to
// R2 ([p*NT+chunk][b][f]) so ln_kernel is unchanged.
// ---------------------------------------------------------------------------
__global__ void __launch_bounds__(256) weighted_v_kernel(
    const float* __restrict__ v1, const float* __restrict__ v2,
    const float* __restrict__ e1, const float* __restrict__ e2,
    float* __restrict__ partial) {
  int g     = blockIdx.x;               // 0..1023
  int b     = g & (B_DIM - 1);
  int chunk = g >> 5;                   // 0..31
  int tid   = threadIdx.x;
  size_t f  = (size_t)tid * 4;
  __shared__ float se1[WV_RPB], se2[WV_RPB];
  if (tid < WV_RPB)
    se1[tid] = e1[(size_t)(chunk + tid * NT) * B_DIM + b];
  else if (tid < 2 * WV_RPB)
    se2[tid - WV_RPB] = e2[(size_t)(chunk + (tid - WV_RPB) * NT) * B_DIM + b];
  __syncthreads();

  float4 c1 = *(const float4*)(v1 + (size_t)g * N_FEAT + f);
  float4 c2 = *(const float4*)(v2 + (size_t)g * N_FEAT + f);
  float4 acc1 = {0.f, 0.f, 0.f, 0.f}, acc2 = {0.f, 0.f, 0.f, 0.f};
  for (int i = 0; i < WV_RPB; i++) {
    int r  = g + (i << 10);
    int rn = (i + 1 < WV_RPB) ? r + WV_BLOCKS : r;
    float4 n1 = *(const float4*)(v1 + (size_t)rn * N_FEAT + f);
    float4 n2 = *(const float4*)(v2 + (size_t)rn * N_FEAT + f);
    float w1 = se1[i], w2 = se2[i];
    acc1.x = fmaf(w1, c1.x, acc1.x); acc1.y = fmaf(w1, c1.y, acc1.y);
    acc1.z = fmaf(w1, c1.z, acc1.z); acc1.w = fmaf(w1, c1.w, acc1.w);
    acc2.x = fmaf(w2, c2.x, acc2.x); acc2.y = fmaf(w2, c2.y, acc2.y);
    acc2.z = fmaf(w2, c2.z, acc2.z); acc2.w = fmaf(w2, c2.w, acc2.w);
    c1 = n1; c2 = n2;
  }
  size_t o1 = ((size_t)(0 * NT + chunk) * B_DIM + b) * N_FEAT + f;
  size_t o2 = ((size_t)(1 * NT + chunk) * B_DIM + b) * N_FEAT + f;
  *(float4*)(partial + o1) = acc1;
  *(float4*)(partial + o2) = acc2;
}

// ---------------------------------------------------------------------------
// Kernel 5: reduce partials, add paths, LayerNorm over feature dim.
// One block per b, 1024 threads (16 waves). (unchanged)
// ---------------------------------------------------------------------------
__device__ __forceinline__ float block_reduce_sum_1024(float v, float* sm) {
#pragma unroll
  for (int off = 32; off > 0; off >>= 1) v += __shfl_down(v, off, 64);
  int wave = threadIdx.x >> 6;
  if ((threadIdx.x & 63) == 0) sm[wave] = v;
  __syncthreads();
  float tot = 0.f;
#pragma unroll
  for (int i = 0; i < 16; i++) tot += sm[i];
  __syncthreads();
  return tot;
}

__global__ void __launch_bounds__(1024) ln_kernel(
    const float* __restrict__ partial, const float* __restrict__ ln_g,
    const float* __restrict__ ln_b, float* __restrict__ out) {
  int b = blockIdx.x;
  int d = threadIdx.x;
  __shared__ float sm[16];
  float x = 0.f;
#pragma unroll
  for (int j = 0; j < 2 * NT; j++)
    x += partial[((size_t)j * B_DIM + b) * N_FEAT + d];
  float ssum = block_reduce_sum_1024(x, sm);
  float mu = ssum * (1.f / N_FEAT);
  float dx = x - mu;
  float vsum = block_reduce_sum_1024(dx * dx, sm);
  float inv = rsqrtf(vsum * (1.f / N_FEAT) + EPS);
  out[(size_t)b * N_FEAT + d] = dx * inv * ln_g[d] + ln_b[d];
}

// ---------------------------------------------------------------------------
extern "C" void kernel_launch(void* const* d_in, const int* in_sizes, int n_in,
                              void* d_out, int out_size, void* d_ws, size_t ws_size,
                              hipStream_t stream) {
  const float* q1     = (const float*)d_in[0];
  const float* k1     = (const float*)d_in[1];
  const float* v1     = (const float*)d_in[2];
  const float* q2     = (const float*)d_in[3];
  const float* k2     = (const float*)d_in[4];
  const float* v2     = (const float*)d_in[5];
  const float* k_mask = (const float*)d_in[6];
  const float* sa_w   = (const float*)d_in[7];
  const float* sa_b   = (const float*)d_in[8];
  const float* a1_w   = (const float*)d_in[9];
  const float* a1_b   = (const float*)d_in[10];
  const float* qk_w   = (const float*)d_in[11];
  const float* qk_b   = (const float*)d_in[12];
  const float* ln_g   = (const float*)d_in[13];
  const float* ln_bp  = (const float*)d_in[14];
  float* out = (float*)d_out;
  float* ws  = (float*)d_ws;

  // ws layout (floats)
  float* sa_q    = ws;                       // 32768
  float* kern_t  = sa_q + 32768;             // 98304  [b][w][c] (transposed!)
  float* s       = kern_t + 98304;           // 98304  [t][b][w]
  float* a1      = s + 98304;                // 32768  [t][b]
  float* e1      = a1 + 32768;               // 32768
  float* e2      = e1 + 32768;               // 32768
  float* partial = e2 + 32768;               // 2*NT*B*N = 2097152 (8 MiB)

  // 1) both GEMVs fused, m-outer for weight reuse; kern written transposed
  prep_kernel<<<dim3((4096 * B_DIM) / 4), 256, 0, stream>>>(
      q1, sa_w, sa_b, q2, qk_w, qk_b, sa_q, kern_t);
  // 2) a1 + conv taps s                  (reads k1, k2: 256 MiB, sequential)
  row_dots_kernel<<<dim3(RD_BLOCKS), 256, 0, stream>>>(
      k1, k2, sa_q, a1_w, kern_t, a1_b, a1, s);
  // 3) softmax both paths
  softmax_kernel<<<dim3(B_DIM), 256, 0, stream>>>(a1, s, k_mask, e1, e2);
  // 4) weighted V sums                   (reads v1, v2: 256 MiB, sequential)
  weighted_v_kernel<<<dim3(WV_BLOCKS), 256, 0, stream>>>(v1, v2, e1, e2, partial);
  // 5) combine + LayerNorm
  ln_kernel<<<dim3(B_DIM), 1024, 0, stream>>>(partial, ln_g, ln_bp, out);
}